// Round 3
// baseline (3583.562 us; speedup 1.0000x reference)
//
#include <hip/hip_runtime.h>
#include <hip/hip_bf16.h>

typedef __bf16 bf16x8 __attribute__((ext_vector_type(8)));
typedef float f32x4 __attribute__((ext_vector_type(4)));

#define TSTEPS 256
#define NB 64
#define ID 1024
#define HD 1024
#define KD 2048

// ws layout (bytes)
#define WOFF 0ull
#define VOFF 16777216ull
#define BOFF 18874368ull
#define HMOFF 18890752ull            // 257 h buffers x 131072 B (bf16 64x1024)
#define BAROFF 52576256ull           // 256 flag dwords (16B aligned)

__device__ __forceinline__ unsigned short f2b(float f) {
    unsigned int u = __float_as_uint(f);
    unsigned int r = (u + 0x7fffu + ((u >> 16) & 1u)) >> 16;
    return (unsigned short)r;
}

__device__ __forceinline__ bf16x8 ldcvt8(const float* p) {
    float4 a = *(const float4*)p;
    float4 b = *(const float4*)(p + 4);
    union { unsigned short h[8]; bf16x8 v; } o;
    o.h[0] = f2b(a.x); o.h[1] = f2b(a.y); o.h[2] = f2b(a.z); o.h[3] = f2b(a.w);
    o.h[4] = f2b(b.x); o.h[5] = f2b(b.y); o.h[6] = f2b(b.z); o.h[7] = f2b(b.w);
    return o.v;
}

// ---- coherence-point (L2-bypass) helpers: flags + h stores ----
__device__ __forceinline__ uint4 ld4_bypass(const unsigned int* p) {
    uint4 r;
    asm volatile("global_load_dwordx4 %0, %1, off sc0 sc1\n\ts_waitcnt vmcnt(0)"
                 : "=v"(r) : "v"(p) : "memory");
    return r;
}
__device__ __forceinline__ void st_dw_bypass(unsigned int* p, unsigned int v) {
    asm volatile("global_store_dword %0, %1, off sc0 sc1\n\ts_waitcnt vmcnt(0)"
                 :: "v"(p), "v"(v) : "memory");
}
__device__ __forceinline__ void st_b64_bypass(unsigned short* p, unsigned long long v) {
    asm volatile("global_store_dwordx2 %0, %1, off sc0 sc1"
                 :: "v"(p), "v"(v) : "memory");
}

__global__ void cvt_w(const float* __restrict__ Wf, const float* __restrict__ Wi,
                      const float* __restrict__ Wo, const float* __restrict__ Wc,
                      const float* __restrict__ bf_, const float* __restrict__ bi_,
                      const float* __restrict__ bo_, const float* __restrict__ bc_,
                      unsigned short* __restrict__ Wr, float* __restrict__ bias_r) {
    int idx = blockIdx.x * 256 + threadIdx.x;   // 4096*256 total
    int np = idx >> 8;            // n' = hcol*4 + gate
    int k  = (idx & 255) * 8;
    int g = np & 3, h = np >> 2;
    const float* W = (g == 0) ? Wf : (g == 1) ? Wi : (g == 2) ? Wo : Wc;
    const float* src = W + (size_t)h * KD + k;
    float4 a = *(const float4*)src;
    float4 b = *(const float4*)(src + 4);
    union { unsigned short h[8]; uint4 u; } o;
    o.h[0] = f2b(a.x); o.h[1] = f2b(a.y); o.h[2] = f2b(a.z); o.h[3] = f2b(a.w);
    o.h[4] = f2b(b.x); o.h[5] = f2b(b.y); o.h[6] = f2b(b.z); o.h[7] = f2b(b.w);
    *(uint4*)(Wr + (size_t)np * KD + k) = o.u;
    if (k == 0) {
        const float* B = (g == 0) ? bf_ : (g == 1) ? bi_ : (g == 2) ? bo_ : bc_;
        bias_r[np] = B[h];
    }
}

__global__ void cvt_v(const float* __restrict__ V, unsigned short* __restrict__ out) {
    size_t i = ((size_t)blockIdx.x * blockDim.x + threadIdx.x) * 8;
    float4 a = *(const float4*)(V + i);
    float4 b = *(const float4*)(V + i + 4);
    union { unsigned short h[8]; uint4 u; } o;
    o.h[0] = f2b(a.x); o.h[1] = f2b(a.y); o.h[2] = f2b(a.z); o.h[3] = f2b(a.w);
    o.h[4] = f2b(b.x); o.h[5] = f2b(b.y); o.h[6] = f2b(b.z); o.h[7] = f2b(b.w);
    *(uint4*)(out + i) = o.u;
}

__global__ void init_h(unsigned short* __restrict__ h0) {
    size_t i = ((size_t)blockIdx.x * blockDim.x + threadIdx.x) * 8;
    uint4 z = {0, 0, 0, 0};
    *(uint4*)(h0 + i) = z;
}

__global__ void init_bar(unsigned int* __restrict__ flags) {
    flags[threadIdx.x] = 0;
}

__device__ __forceinline__ float sigf(float x) {
    return 1.0f / (1.0f + __expf(-x));
}
__device__ __forceinline__ float tanhfast(float x) {
    // tanh(x) = 2*sigmoid(2x) - 1; saturates correctly (exp->inf => -1, exp->0 => +1)
    return 2.0f / (1.0f + __expf(-2.0f * x)) - 1.0f;
}

__launch_bounds__(512, 2)
__global__ void lstm_core(const float* __restrict__ xf,
                          const unsigned short* __restrict__ Wr,
                          const float* __restrict__ bias_r,
                          unsigned short* __restrict__ hm,
                          const unsigned short* __restrict__ Vw,
                          const float* __restrict__ Vbias,
                          float* __restrict__ out,
                          unsigned int* __restrict__ flags) {
    __shared__ float gxp[8][64][20];
    __shared__ unsigned short hg[64][4];
    __shared__ int ready;

    const int bid  = blockIdx.x;       // 256 blocks, each owns 16 gate-cols (4 h-cols)
    const int tid  = threadIdx.x;      // 512 threads, 8 waves
    const int wave = tid >> 6;
    const int lane = tid & 63;
    const int lrow = lane & 15;
    const int kq   = (lane >> 4) << 3; // 0,8,16,24
    const int n0   = bid << 4;
    const int qr   = (lane >> 4) << 2;

    // cell-update mapping: waves 4-7 (tid 256..511) double as the 256 cell threads
    const int ct   = tid - 256;
    const int ob   = (ct >> 2) & 63;
    const int lhc  = ct & 3;
    const int hcol = (bid << 2) + lhc;
    float4 bb = {0,0,0,0};
    if (tid >= 256) bb = *(const float4*)&bias_r[n0 + (lhc << 2)];

    const bool isx = wave < 4;
    // weight pointer: wave's K-slice (256 of 2048): x-waves k 0..1023, h-waves 1024..2047
    const unsigned short* wptr = Wr + (size_t)(n0 + lrow) * KD + (wave << 8) + kq;

    // x row bases (f32, converted on the fly): waves 0-3 cover k 0..1023
    const float* xrow[4];
    size_t hoffb[4];
    if (isx) {
        int ko = (wave << 8) + kq;
        #pragma unroll
        for (int m = 0; m < 4; ++m)
            xrow[m] = xf + (size_t)(m * 16 + lrow) * (TSTEPS * ID) + ko;
    } else {
        int ko = ((wave - 4) << 8) + kq;
        #pragma unroll
        for (int m = 0; m < 4; ++m)
            hoffb[m] = (size_t)(m * 16 + lrow) * HD + ko;
    }

    if (tid == 0) *(volatile int*)&ready = -1;
    __syncthreads();

    float c_reg = 0.f;
    float hlast = 0.f;

    for (int t = 0; t < TSTEPS; ++t) {
        f32x4 acc0 = {0,0,0,0}, acc1 = {0,0,0,0}, acc2 = {0,0,0,0}, acc3 = {0,0,0,0};

        if (isx) {
            // x-part: independent of h — runs during other blocks' cell/flag latency
            const size_t aoff = (size_t)t * ID;
            const float* a0 = xrow[0] + aoff;
            const float* a1 = xrow[1] + aoff;
            const float* a2 = xrow[2] + aoff;
            const float* a3 = xrow[3] + aoff;
            #pragma unroll
            for (int kk = 0; kk < 256; kk += 32) {
                bf16x8 bfrag = *(const bf16x8*)(wptr + kk);
                acc0 = __builtin_amdgcn_mfma_f32_16x16x32_bf16(ldcvt8(a0 + kk), bfrag, acc0, 0, 0, 0);
                acc1 = __builtin_amdgcn_mfma_f32_16x16x32_bf16(ldcvt8(a1 + kk), bfrag, acc1, 0, 0, 0);
                acc2 = __builtin_amdgcn_mfma_f32_16x16x32_bf16(ldcvt8(a2 + kk), bfrag, acc2, 0, 0, 0);
                acc3 = __builtin_amdgcn_mfma_f32_16x16x32_bf16(ldcvt8(a3 + kk), bfrag, acc3, 0, 0, 0);
            }
        } else {
            // wait for all blocks' h_t to be visible at the coherence point
            if (wave == 4) {
                const unsigned int* fp = flags + (lane << 2);
                for (;;) {
                    uint4 f = ld4_bypass(fp);
                    bool ok = f.x >= (unsigned)t && f.y >= (unsigned)t &&
                              f.z >= (unsigned)t && f.w >= (unsigned)t;
                    if (__all(ok)) break;
                    __builtin_amdgcn_s_sleep(1);
                }
                if (lane == 0) *(volatile int*)&ready = t;
            } else {
                while (*(volatile int*)&ready < t) __builtin_amdgcn_s_sleep(1);
            }
            __builtin_amdgcn_sched_barrier(0);
            // plain cached loads: h_t buffer addresses are virgin this launch,
            // so per-XCD L2 serves 32 blocks from one L3 fetch
            const unsigned short* hb = hm + (size_t)t * (NB * HD);
            const unsigned short* a0 = hb + hoffb[0];
            const unsigned short* a1 = hb + hoffb[1];
            const unsigned short* a2 = hb + hoffb[2];
            const unsigned short* a3 = hb + hoffb[3];
            #pragma unroll
            for (int kk = 0; kk < 256; kk += 32) {
                bf16x8 bfrag = *(const bf16x8*)(wptr + kk);
                acc0 = __builtin_amdgcn_mfma_f32_16x16x32_bf16(*(const bf16x8*)(a0 + kk), bfrag, acc0, 0, 0, 0);
                acc1 = __builtin_amdgcn_mfma_f32_16x16x32_bf16(*(const bf16x8*)(a1 + kk), bfrag, acc1, 0, 0, 0);
                acc2 = __builtin_amdgcn_mfma_f32_16x16x32_bf16(*(const bf16x8*)(a2 + kk), bfrag, acc2, 0, 0, 0);
                acc3 = __builtin_amdgcn_mfma_f32_16x16x32_bf16(*(const bf16x8*)(a3 + kk), bfrag, acc3, 0, 0, 0);
            }
        }

        #pragma unroll
        for (int r = 0; r < 4; ++r) gxp[wave][ 0 + qr + r][lrow] = acc0[r];
        #pragma unroll
        for (int r = 0; r < 4; ++r) gxp[wave][16 + qr + r][lrow] = acc1[r];
        #pragma unroll
        for (int r = 0; r < 4; ++r) gxp[wave][32 + qr + r][lrow] = acc2[r];
        #pragma unroll
        for (int r = 0; r < 4; ++r) gxp[wave][48 + qr + r][lrow] = acc3[r];
        __syncthreads();   // S1: gate partials ready

        if (tid >= 256) {
            float fpre = bb.x, ipre = bb.y, opre = bb.z, gpre = bb.w;
            #pragma unroll
            for (int w = 0; w < 8; ++w) {
                float4 s = *(const float4*)&gxp[w][ob][lhc << 2];
                fpre += s.x; ipre += s.y; opre += s.z; gpre += s.w;
            }
            float fg = sigf(fpre);
            float ig = sigf(ipre);
            float og = sigf(opre);
            float gg = tanhfast(gpre);
            c_reg = fg * c_reg + ig * gg;
            float hh = og * tanhfast(c_reg);
            hg[ob][lhc] = f2b(hh);
            asm volatile("s_waitcnt lgkmcnt(0)" ::: "memory");
            __builtin_amdgcn_sched_barrier(0);
            if (lhc == 0) {
                unsigned long long v = *(const unsigned long long*)&hg[ob][0];
                st_b64_bypass(hm + (size_t)(t + 1) * (NB * HD) + (size_t)ob * HD + (bid << 2), v);
                asm volatile("s_waitcnt vmcnt(0)" ::: "memory");
            }
            if (t == TSTEPS - 1) hlast = hh;
        }
        __syncthreads();   // S2: all h-stores of this block acked at coherence point

        if (tid == 256) st_dw_bypass(&flags[bid], (unsigned int)(t + 1));
    }

    if (tid >= 256) {
        out[(size_t)ob * HD + hcol] = c_reg;                    // c
        out[65536 + (size_t)ob * HD + hcol] = hlast;            // h
    }

    // final projection: last_out = h_256 @ V^T + V_b, blocks 0..63 (N=1024)
    if (bid < 64) {
        {   // wait until every block has published h_256
            const unsigned int* fp = flags + (lane << 2);
            for (;;) {
                uint4 f = ld4_bypass(fp);
                bool ok = f.x >= 256u && f.y >= 256u && f.z >= 256u && f.w >= 256u;
                if (__all(ok)) break;
                __builtin_amdgcn_s_sleep(1);
            }
        }
        __builtin_amdgcn_sched_barrier(0);
        f32x4 acc0 = {0,0,0,0}, acc1 = {0,0,0,0}, acc2 = {0,0,0,0}, acc3 = {0,0,0,0};
        const int ko = (wave << 7) + kq;                        // K=1024 split 8 x 128
        const unsigned short* vp = Vw + (size_t)(n0 + lrow) * HD + ko;
        const unsigned short* h0 = hm + (size_t)TSTEPS * (NB * HD) + (size_t)lrow * HD + ko;
        #pragma unroll
        for (int kk = 0; kk < 128; kk += 32) {
            bf16x8 bfrag = *(const bf16x8*)(vp + kk);
            acc0 = __builtin_amdgcn_mfma_f32_16x16x32_bf16(*(const bf16x8*)(h0 + kk),           bfrag, acc0, 0, 0, 0);
            acc1 = __builtin_amdgcn_mfma_f32_16x16x32_bf16(*(const bf16x8*)(h0 + 16 * HD + kk), bfrag, acc1, 0, 0, 0);
            acc2 = __builtin_amdgcn_mfma_f32_16x16x32_bf16(*(const bf16x8*)(h0 + 32 * HD + kk), bfrag, acc2, 0, 0, 0);
            acc3 = __builtin_amdgcn_mfma_f32_16x16x32_bf16(*(const bf16x8*)(h0 + 48 * HD + kk), bfrag, acc3, 0, 0, 0);
        }
        #pragma unroll
        for (int r = 0; r < 4; ++r) gxp[wave][ 0 + qr + r][lrow] = acc0[r];
        #pragma unroll
        for (int r = 0; r < 4; ++r) gxp[wave][16 + qr + r][lrow] = acc1[r];
        #pragma unroll
        for (int r = 0; r < 4; ++r) gxp[wave][32 + qr + r][lrow] = acc2[r];
        #pragma unroll
        for (int r = 0; r < 4; ++r) gxp[wave][48 + qr + r][lrow] = acc3[r];
        __syncthreads();
        if (tid >= 256) {
            float4 vb = *(const float4*)&Vbias[n0 + (lhc << 2)];
            float4 res = vb;
            #pragma unroll
            for (int w = 0; w < 8; ++w) {
                float4 s = *(const float4*)&gxp[w][ob][lhc << 2];
                res.x += s.x; res.y += s.y; res.z += s.z; res.w += s.w;
            }
            *(float4*)&out[131072 + (size_t)ob * 1024 + n0 + (lhc << 2)] = res;
        }
    }
}

extern "C" void kernel_launch(void* const* d_in, const int* in_sizes, int n_in,
                              void* d_out, int out_size, void* d_ws, size_t ws_size,
                              hipStream_t stream) {
    const float* x   = (const float*)d_in[0];
    const float* Wf  = (const float*)d_in[1];
    const float* bf_ = (const float*)d_in[2];
    const float* Wi  = (const float*)d_in[3];
    const float* bi_ = (const float*)d_in[4];
    const float* Wc  = (const float*)d_in[5];
    const float* bc_ = (const float*)d_in[6];
    const float* Wo  = (const float*)d_in[7];
    const float* bo_ = (const float*)d_in[8];
    const float* Vw  = (const float*)d_in[9];
    const float* Vb  = (const float*)d_in[10];

    char* ws = (char*)d_ws;
    unsigned short* Wr     = (unsigned short*)(ws + WOFF);
    unsigned short* Vbf    = (unsigned short*)(ws + VOFF);
    float*          bias_r = (float*)(ws + BOFF);
    unsigned short* hm     = (unsigned short*)(ws + HMOFF);
    unsigned int*   flags  = (unsigned int*)(ws + BAROFF);
    float*          outp   = (float*)d_out;

    cvt_w <<<4096, 256, 0, stream>>>(Wf, Wi, Wo, Wc, bf_, bi_, bo_, bc_, Wr, bias_r);
    cvt_v <<<512, 256, 0, stream>>>(Vw, Vbf);
    init_h<<<32, 256, 0, stream>>>(hm);
    init_bar<<<1, 256, 0, stream>>>(flags);

    void* args[] = {(void*)&x, &Wr, &bias_r, &hm, &Vbf, (void*)&Vb, &outp, &flags};
    hipLaunchCooperativeKernel((const void*)lstm_core, dim3(256), dim3(512), args, 0, stream);
}

// Round 5
// 2470.837 us; speedup vs baseline: 1.4503x; 1.4503x over previous
//
#include <hip/hip_runtime.h>
#include <hip/hip_bf16.h>

typedef __bf16 bf16x8 __attribute__((ext_vector_type(8)));
typedef float f32x4 __attribute__((ext_vector_type(4)));
typedef unsigned long long u64;

#define TSTEPS 256
#define NB 64
#define ID 1024
#define HD 1024
#define KD 2048

// ws layout (bytes)
#define WOFF 0ull
#define VOFF 16777216ull
#define BOFF 18874368ull
#define HMOFF 18890752ull            // 257 h buffers x 65536 elems (bf16), block-major interleaved
#define BAROFF 52576256ull           // 256 flags, 1 dword per 16B (4KB)
#define XBOFF 52580352ull            // xb bf16 [t][row][k] = 33.5MB

__device__ __forceinline__ unsigned short f2b(float f) {
    unsigned int u = __float_as_uint(f);
    unsigned int r = (u + 0x7fffu + ((u >> 16) & 1u)) >> 16;
    return (unsigned short)r;
}

__device__ __forceinline__ bf16x8 frag2(u64 lo, u64 hi) {
    union { u64 q[2]; bf16x8 v; } c; c.q[0] = lo; c.q[1] = hi; return c.v;
}

__global__ void cvt_x(const float* __restrict__ in, unsigned short* __restrict__ out) {
    size_t i = ((size_t)blockIdx.x * 256 + threadIdx.x) * 8;
    int t = (int)(i >> 16);
    int b = (int)(i >> 10) & 63;
    int k = (int)i & 1023;
    const float* src = in + ((size_t)b << 18) + ((size_t)t << 10) + k;  // x[b][t][k]
    float4 a = *(const float4*)src;
    float4 bb = *(const float4*)(src + 4);
    union { unsigned short h[8]; uint4 u; } o;
    o.h[0] = f2b(a.x); o.h[1] = f2b(a.y); o.h[2] = f2b(a.z); o.h[3] = f2b(a.w);
    o.h[4] = f2b(bb.x); o.h[5] = f2b(bb.y); o.h[6] = f2b(bb.z); o.h[7] = f2b(bb.w);
    *(uint4*)(out + i) = o.u;   // xb[t][b][k]
}

__global__ void cvt_w(const float* __restrict__ Wf, const float* __restrict__ Wi,
                      const float* __restrict__ Wo, const float* __restrict__ Wc,
                      const float* __restrict__ bf_, const float* __restrict__ bi_,
                      const float* __restrict__ bo_, const float* __restrict__ bc_,
                      unsigned short* __restrict__ Wr, float* __restrict__ bias_r) {
    int idx = blockIdx.x * 256 + threadIdx.x;   // 4096*256 total
    int np = idx >> 8;            // n' = hcol*4 + gate
    int k  = (idx & 255) * 8;
    int g = np & 3, h = np >> 2;
    const float* W = (g == 0) ? Wf : (g == 1) ? Wi : (g == 2) ? Wo : Wc;
    const float* src = W + (size_t)h * KD + k;
    float4 a = *(const float4*)src;
    float4 b = *(const float4*)(src + 4);
    union { unsigned short h[8]; uint4 u; } o;
    o.h[0] = f2b(a.x); o.h[1] = f2b(a.y); o.h[2] = f2b(a.z); o.h[3] = f2b(a.w);
    o.h[4] = f2b(b.x); o.h[5] = f2b(b.y); o.h[6] = f2b(b.z); o.h[7] = f2b(b.w);
    *(uint4*)(Wr + (size_t)np * KD + k) = o.u;
    if (k == 0) {
        const float* B = (g == 0) ? bf_ : (g == 1) ? bi_ : (g == 2) ? bo_ : bc_;
        bias_r[np] = B[h];
    }
}

__global__ void cvt_v(const float* __restrict__ V, unsigned short* __restrict__ out) {
    size_t i = ((size_t)blockIdx.x * blockDim.x + threadIdx.x) * 8;
    float4 a = *(const float4*)(V + i);
    float4 b = *(const float4*)(V + i + 4);
    union { unsigned short h[8]; uint4 u; } o;
    o.h[0] = f2b(a.x); o.h[1] = f2b(a.y); o.h[2] = f2b(a.z); o.h[3] = f2b(a.w);
    o.h[4] = f2b(b.x); o.h[5] = f2b(b.y); o.h[6] = f2b(b.z); o.h[7] = f2b(b.w);
    *(uint4*)(out + i) = o.u;
}

__global__ void init_h(unsigned short* __restrict__ h0) {
    size_t i = ((size_t)blockIdx.x * blockDim.x + threadIdx.x) * 8;
    uint4 z = {0, 0, 0, 0};
    *(uint4*)(h0 + i) = z;
}

__global__ void init_bar(unsigned int* __restrict__ flags) {
    flags[blockIdx.x * 256 + threadIdx.x] = 0;
}

__device__ __forceinline__ float sigf(float x) {
    return 1.0f / (1.0f + __expf(-x));
}
__device__ __forceinline__ float tanhfast(float x) {
    return 2.0f / (1.0f + __expf(-2.0f * x)) - 1.0f;
}

// poll all 256 flags (stride-4 dwords); lane covers bids l, l+64, l+128, l+192
__device__ __forceinline__ bool flags_ge(const unsigned int* fp, unsigned int t) {
    unsigned int f0, f1, f2, f3;
    asm volatile("global_load_dword %0, %4, off sc0 sc1\n\t"
                 "global_load_dword %1, %4, off offset:1024 sc0 sc1\n\t"
                 "global_load_dword %2, %4, off offset:2048 sc0 sc1\n\t"
                 "global_load_dword %3, %4, off offset:3072 sc0 sc1\n\t"
                 "s_waitcnt vmcnt(0)"
                 : "=&v"(f0), "=&v"(f1), "=&v"(f2), "=&v"(f3) : "v"(fp) : "memory");
    bool ok = f0 >= t && f1 >= t && f2 >= t && f3 >= t;
    return __all(ok) != 0;
}

__launch_bounds__(512, 2)
__global__ void lstm_core(const unsigned short* __restrict__ xb,
                          const unsigned short* __restrict__ Wr,
                          const float* __restrict__ bias_r,
                          unsigned short* __restrict__ hm,
                          const unsigned short* __restrict__ Vw,
                          const float* __restrict__ Vbias,
                          float* __restrict__ out,
                          unsigned int* __restrict__ flags) {
    __shared__ float gxp[8][64][20];
    __shared__ __align__(8) unsigned short hg[64][4];
    __shared__ int ready;

    const int bid  = blockIdx.x;       // 256 blocks, 16 gate-cols (4 h-cols) each
    const int tid  = threadIdx.x;      // 512 threads, 8 waves
    const int wave = tid >> 6;
    const int lane = tid & 63;
    const int lrow = lane & 15;
    const int kq   = (lane >> 4) << 3; // 0,8,16,24
    const int n0   = bid << 4;
    const int qr   = (lane >> 4) << 2;

    // cell mapping: waves 4-7 (tid 256..511) are the 256 cell threads
    const int ct   = tid - 256;
    const int ob   = (ct >> 2) & 63;
    const int lhc  = ct & 3;
    const int hcol = (bid << 2) + lhc;
    float4 bb = {0, 0, 0, 0};
    if (tid >= 256) bb = *(const float4*)&bias_r[n0 + (lhc << 2)];

    const bool isx = wave < 4;
    // wptr includes (wave<<8): x-waves cover k 0..1023, h-waves k 1024..2047
    const unsigned short* wptr = Wr + (size_t)(n0 + lrow) * KD + (wave << 8) + kq;

    int koff = 0;
    if (!isx) koff = ((wave - 4) << 8) + kq;   // h-col base for this lane

    if (tid == 0) *(volatile int*)&ready = -1;
    __syncthreads();

    float c_reg = 0.f;
    float hlast = 0.f;

    for (int t = 0; t < TSTEPS; ++t) {
        f32x4 acc[4];
        #pragma unroll
        for (int m = 0; m < 4; ++m) acc[m] = (f32x4){0, 0, 0, 0};

        if (isx) {
            const unsigned short* xt = xb + ((size_t)t << 16);
            #pragma unroll
            for (int kk = 0; kk < 256; kk += 32) {
                bf16x8 bfrag = *(const bf16x8*)(wptr + kk);
                #pragma unroll
                for (int m = 0; m < 4; ++m)
                    acc[m] = __builtin_amdgcn_mfma_f32_16x16x32_bf16(
                        *(const bf16x8*)(xt + (size_t)(m * 16 + lrow) * 1024 + ((wave << 8) + kq) + kk),
                        bfrag, acc[m], 0, 0, 0);
            }
        } else {
            if (wave == 4) {
                const unsigned int* fp = flags + (lane << 2);
                int iters = 0;
                while (!flags_ge(fp, (unsigned int)t)) {
                    if (++iters > (1 << 22)) break;
                    __builtin_amdgcn_s_sleep(1);
                }
                if (lane == 0) *(volatile int*)&ready = t;
            } else {
                int iters = 0;
                while (*(volatile int*)&ready < t) {
                    if (++iters > (1 << 24)) break;
                    __builtin_amdgcn_s_sleep(1);
                }
            }
            __builtin_amdgcn_sched_barrier(0);
            // h_t: virgin addresses, plain cached loads (L2 shares one L3 fetch per XCD)
            const unsigned short* hmt = hm + ((size_t)t << 16);
            #pragma unroll
            for (int kk = 0; kk < 256; kk += 32) {
                bf16x8 bfrag = *(const bf16x8*)(wptr + kk);   // wptr already holds the h k-offset
                int cb = (koff + kk) >> 2;                    // chunk index
                #pragma unroll
                for (int m = 0; m < 4; ++m) {
                    const unsigned short* p = hmt + (size_t)cb * 256 + (m * 16 + lrow) * 4;
                    u64 lo = *(const u64*)p;
                    u64 hi = *(const u64*)(p + 256);
                    acc[m] = __builtin_amdgcn_mfma_f32_16x16x32_bf16(frag2(lo, hi), bfrag, acc[m], 0, 0, 0);
                }
            }
        }

        #pragma unroll
        for (int m = 0; m < 4; ++m)
            #pragma unroll
            for (int r = 0; r < 4; ++r)
                gxp[wave][m * 16 + qr + r][lrow] = acc[m][r];
        __syncthreads();   // S1: gate partials ready

        if (tid >= 256) {
            float fpre = bb.x, ipre = bb.y, opre = bb.z, gpre = bb.w;
            #pragma unroll
            for (int w = 0; w < 8; ++w) {
                float4 s = *(const float4*)&gxp[w][ob][lhc << 2];
                fpre += s.x; ipre += s.y; opre += s.z; gpre += s.w;
            }
            float fg = sigf(fpre);
            float ig = sigf(ipre);
            float og = sigf(opre);
            float gg = tanhfast(gpre);
            c_reg = fg * c_reg + ig * gg;
            float hh = og * tanhfast(c_reg);
            hg[ob][lhc] = f2b(hh);
            if (t == TSTEPS - 1) hlast = hh;
        }
        __syncthreads();   // S2: hg complete; gxp consumed

        // wave 7 alone publishes h (one coalesced 512B store) then the flag;
        // waves 0-6 charge ahead into step t+1
        if (wave == 7) {
            u64 v = *(const u64*)&hg[lane][0];
            unsigned short* dst = hm + ((size_t)(t + 1) << 16) + (size_t)bid * 256 + lane * 4;
            asm volatile("global_store_dwordx2 %0, %1, off sc0 sc1" :: "v"(dst), "v"(v) : "memory");
            asm volatile("s_waitcnt vmcnt(0)" ::: "memory");
            if (lane == 0) {
                unsigned int* fdst = flags + (bid << 2);
                unsigned int fv = (unsigned int)(t + 1);
                asm volatile("global_store_dword %0, %1, off sc0 sc1" :: "v"(fdst), "v"(fv) : "memory");
            }
        }
    }

    if (tid >= 256) {
        out[(size_t)ob * HD + hcol] = c_reg;                    // c
        out[65536 + (size_t)ob * HD + hcol] = hlast;            // h
    }

    // final projection: last_out = h_256 @ V^T + V_b, blocks 0..63 (N=1024)
    if (bid < 64) {
        {
            const unsigned int* fp = flags + (lane << 2);
            int iters = 0;
            while (!flags_ge(fp, 256u)) {
                if (++iters > (1 << 22)) break;
                __builtin_amdgcn_s_sleep(1);
            }
        }
        __builtin_amdgcn_sched_barrier(0);
        f32x4 acc[4];
        #pragma unroll
        for (int m = 0; m < 4; ++m) acc[m] = (f32x4){0, 0, 0, 0};
        const int ko2 = (wave << 7) + kq;                       // K=1024 split 8 x 128
        const unsigned short* vp = Vw + (size_t)(n0 + lrow) * HD + ko2;
        const unsigned short* hmt = hm + ((size_t)TSTEPS << 16);
        #pragma unroll
        for (int kk = 0; kk < 128; kk += 32) {
            bf16x8 bfrag = *(const bf16x8*)(vp + kk);
            int cb = (ko2 + kk) >> 2;
            #pragma unroll
            for (int m = 0; m < 4; ++m) {
                const unsigned short* p = hmt + (size_t)cb * 256 + (m * 16 + lrow) * 4;
                u64 lo = *(const u64*)p;
                u64 hi = *(const u64*)(p + 256);
                acc[m] = __builtin_amdgcn_mfma_f32_16x16x32_bf16(frag2(lo, hi), bfrag, acc[m], 0, 0, 0);
            }
        }
        #pragma unroll
        for (int m = 0; m < 4; ++m)
            #pragma unroll
            for (int r = 0; r < 4; ++r)
                gxp[wave][m * 16 + qr + r][lrow] = acc[m][r];
        __syncthreads();
        if (tid >= 256) {
            float4 vb = *(const float4*)&Vbias[n0 + (lhc << 2)];
            float4 res = vb;
            #pragma unroll
            for (int w = 0; w < 8; ++w) {
                float4 s = *(const float4*)&gxp[w][ob][lhc << 2];
                res.x += s.x; res.y += s.y; res.z += s.z; res.w += s.w;
            }
            *(float4*)&out[131072 + (size_t)ob * 1024 + n0 + (lhc << 2)] = res;
        }
    }
}

extern "C" void kernel_launch(void* const* d_in, const int* in_sizes, int n_in,
                              void* d_out, int out_size, void* d_ws, size_t ws_size,
                              hipStream_t stream) {
    const float* x   = (const float*)d_in[0];
    const float* Wf  = (const float*)d_in[1];
    const float* bf_ = (const float*)d_in[2];
    const float* Wi  = (const float*)d_in[3];
    const float* bi_ = (const float*)d_in[4];
    const float* Wc  = (const float*)d_in[5];
    const float* bc_ = (const float*)d_in[6];
    const float* Wo  = (const float*)d_in[7];
    const float* bo_ = (const float*)d_in[8];
    const float* Vw  = (const float*)d_in[9];
    const float* Vb  = (const float*)d_in[10];

    char* ws = (char*)d_ws;
    unsigned short* Wr     = (unsigned short*)(ws + WOFF);
    unsigned short* Vbf    = (unsigned short*)(ws + VOFF);
    float*          bias_r = (float*)(ws + BOFF);
    unsigned short* hm     = (unsigned short*)(ws + HMOFF);
    unsigned int*   flags  = (unsigned int*)(ws + BAROFF);
    unsigned short* xbb    = (unsigned short*)(ws + XBOFF);
    float*          outp   = (float*)d_out;

    cvt_x <<<8192, 256, 0, stream>>>(x, xbb);
    cvt_w <<<4096, 256, 0, stream>>>(Wf, Wi, Wo, Wc, bf_, bi_, bo_, bc_, Wr, bias_r);
    cvt_v <<<512, 256, 0, stream>>>(Vw, Vbf);
    init_h<<<32, 256, 0, stream>>>(hm);
    init_bar<<<4, 256, 0, stream>>>(flags);

    void* args[] = {&xbb, &Wr, &bias_r, &hm, &Vbf, (void*)&Vb, &outp, &flags};
    hipLaunchCooperativeKernel((const void*)lstm_core, dim3(256), dim3(512), args, 0, stream);
}

// Round 6
// 2458.782 us; speedup vs baseline: 1.4575x; 1.0049x over previous
//
#include <hip/hip_runtime.h>
#include <hip/hip_bf16.h>

typedef __bf16 bf16x8 __attribute__((ext_vector_type(8)));
typedef float f32x4 __attribute__((ext_vector_type(4)));
typedef unsigned long long u64;

#define TSTEPS 256
#define NB 64
#define ID 1024
#define HD 1024
#define KD 2048

// ws layout (bytes)
#define WOFF 0ull
#define VOFF 16777216ull
#define BOFF 18874368ull
#define HMOFF 18890752ull            // 257 h buffers x 65536 elems (bf16), block-major interleaved
#define BAROFF 52576256ull           // 256 packed flag dwords (1KB)
#define XBOFF 52580352ull            // xb bf16 [t][row][k] = 33.5MB

__device__ __forceinline__ unsigned short f2b(float f) {
    unsigned int u = __float_as_uint(f);
    unsigned int r = (u + 0x7fffu + ((u >> 16) & 1u)) >> 16;
    return (unsigned short)r;
}

__device__ __forceinline__ bf16x8 frag2(u64 lo, u64 hi) {
    union { u64 q[2]; bf16x8 v; } c; c.q[0] = lo; c.q[1] = hi; return c.v;
}

__global__ void cvt_x(const float* __restrict__ in, unsigned short* __restrict__ out) {
    size_t i = ((size_t)blockIdx.x * 256 + threadIdx.x) * 8;
    int t = (int)(i >> 16);
    int b = (int)(i >> 10) & 63;
    int k = (int)i & 1023;
    const float* src = in + ((size_t)b << 18) + ((size_t)t << 10) + k;  // x[b][t][k]
    float4 a = *(const float4*)src;
    float4 bb = *(const float4*)(src + 4);
    union { unsigned short h[8]; uint4 u; } o;
    o.h[0] = f2b(a.x); o.h[1] = f2b(a.y); o.h[2] = f2b(a.z); o.h[3] = f2b(a.w);
    o.h[4] = f2b(bb.x); o.h[5] = f2b(bb.y); o.h[6] = f2b(bb.z); o.h[7] = f2b(bb.w);
    *(uint4*)(out + i) = o.u;   // xb[t][b][k]
}

__global__ void cvt_w(const float* __restrict__ Wf, const float* __restrict__ Wi,
                      const float* __restrict__ Wo, const float* __restrict__ Wc,
                      const float* __restrict__ bf_, const float* __restrict__ bi_,
                      const float* __restrict__ bo_, const float* __restrict__ bc_,
                      unsigned short* __restrict__ Wr, float* __restrict__ bias_r) {
    int idx = blockIdx.x * 256 + threadIdx.x;   // 4096*256 total
    int np = idx >> 8;            // n' = hcol*4 + gate
    int k  = (idx & 255) * 8;
    int g = np & 3, h = np >> 2;
    const float* W = (g == 0) ? Wf : (g == 1) ? Wi : (g == 2) ? Wo : Wc;
    const float* src = W + (size_t)h * KD + k;
    float4 a = *(const float4*)src;
    float4 b = *(const float4*)(src + 4);
    union { unsigned short h[8]; uint4 u; } o;
    o.h[0] = f2b(a.x); o.h[1] = f2b(a.y); o.h[2] = f2b(a.z); o.h[3] = f2b(a.w);
    o.h[4] = f2b(b.x); o.h[5] = f2b(b.y); o.h[6] = f2b(b.z); o.h[7] = f2b(b.w);
    *(uint4*)(Wr + (size_t)np * KD + k) = o.u;
    if (k == 0) {
        const float* B = (g == 0) ? bf_ : (g == 1) ? bi_ : (g == 2) ? bo_ : bc_;
        bias_r[np] = B[h];
    }
}

__global__ void cvt_v(const float* __restrict__ V, unsigned short* __restrict__ out) {
    size_t i = ((size_t)blockIdx.x * blockDim.x + threadIdx.x) * 8;
    float4 a = *(const float4*)(V + i);
    float4 b = *(const float4*)(V + i + 4);
    union { unsigned short h[8]; uint4 u; } o;
    o.h[0] = f2b(a.x); o.h[1] = f2b(a.y); o.h[2] = f2b(a.z); o.h[3] = f2b(a.w);
    o.h[4] = f2b(b.x); o.h[5] = f2b(b.y); o.h[6] = f2b(b.z); o.h[7] = f2b(b.w);
    *(uint4*)(out + i) = o.u;
}

__global__ void init_h(unsigned short* __restrict__ h0) {
    size_t i = ((size_t)blockIdx.x * blockDim.x + threadIdx.x) * 8;
    uint4 z = {0, 0, 0, 0};
    *(uint4*)(h0 + i) = z;
}

__global__ void init_bar(unsigned int* __restrict__ flags) {
    flags[threadIdx.x] = 0;
}

__device__ __forceinline__ float sigf(float x) {
    return 1.0f / (1.0f + __expf(-x));
}
__device__ __forceinline__ float tanhfast(float x) {
    return 2.0f / (1.0f + __expf(-2.0f * x)) - 1.0f;
}

// poll all 256 packed flags: one dwordx4 per lane (lane covers 4 contiguous blocks)
__device__ __forceinline__ bool flags_ge(const unsigned int* fp, unsigned int t) {
    uint4 f;
    asm volatile("global_load_dwordx4 %0, %1, off sc0 sc1\n\ts_waitcnt vmcnt(0)"
                 : "=v"(f) : "v"(fp) : "memory");
    bool ok = f.x >= t && f.y >= t && f.z >= t && f.w >= t;
    return __all(ok) != 0;
}

__launch_bounds__(512, 2)
__global__ void lstm_core(const unsigned short* __restrict__ xb,
                          const unsigned short* __restrict__ Wr,
                          const float* __restrict__ bias_r,
                          unsigned short* __restrict__ hm,
                          const unsigned short* __restrict__ Vw,
                          const float* __restrict__ Vbias,
                          float* __restrict__ out,
                          unsigned int* __restrict__ flags) {
    __shared__ float gxp[8][64][20];
    __shared__ int cnt;

    const int bid  = blockIdx.x;       // 256 blocks, 16 gate-cols (4 h-cols) each
    const int tid  = threadIdx.x;      // 512 threads, 8 waves
    const int wave = tid >> 6;
    const int lane = tid & 63;
    const int lrow = lane & 15;
    const int kq   = (lane >> 4) << 3; // 0,8,16,24
    const int n0   = bid << 4;
    const int qr   = (lane >> 4) << 2;

    // cell mapping: waves 4-7 (tid 256..511) are the 256 cell threads
    const int ct   = tid - 256;
    const int ob   = (ct >> 2) & 63;
    const int lhc  = ct & 3;
    const int hcol = (bid << 2) + lhc;
    float4 bb = {0, 0, 0, 0};
    if (tid >= 256) bb = *(const float4*)&bias_r[n0 + (lhc << 2)];

    const bool isx = wave < 4;
    // wptr includes (wave<<8): x-waves cover k 0..1023, h-waves k 1024..2047
    const unsigned short* wptr = Wr + (size_t)(n0 + lrow) * KD + (wave << 8) + kq;

    // loop-invariant weight fragments in registers (32 VGPR)
    bf16x8 wfrag[8];
    #pragma unroll
    for (int kk8 = 0; kk8 < 8; ++kk8)
        wfrag[kk8] = *(const bf16x8*)(wptr + kk8 * 32);

    int koff = 0;
    if (!isx) koff = ((wave - 4) << 8) + kq;   // h-col base for this lane
    const int xko = (wave << 8) + kq;

    if (tid == 0) *(volatile int*)&cnt = 0;
    __syncthreads();

    float c_reg = 0.f;
    float hlast = 0.f;

    for (int t = 0; t < TSTEPS; ++t) {
        f32x4 acc[4];
        #pragma unroll
        for (int m = 0; m < 4; ++m) acc[m] = (f32x4){0, 0, 0, 0};

        if (isx) {
            const unsigned short* xt = xb + ((size_t)t << 16);
            // preload all 32 A-fragments into registers, then register-only MFMA
            bf16x8 xv[4][8];
            #pragma unroll
            for (int m = 0; m < 4; ++m)
                #pragma unroll
                for (int kk8 = 0; kk8 < 8; ++kk8)
                    xv[m][kk8] = *(const bf16x8*)(xt + (size_t)(m * 16 + lrow) * 1024 + xko + kk8 * 32);
            #pragma unroll
            for (int kk8 = 0; kk8 < 8; ++kk8)
                #pragma unroll
                for (int m = 0; m < 4; ++m)
                    acc[m] = __builtin_amdgcn_mfma_f32_16x16x32_bf16(xv[m][kk8], wfrag[kk8], acc[m], 0, 0, 0);
        } else {
            // all 4 h-waves poll the packed flags directly
            const unsigned int* fp = flags + (lane << 2);
            int iters = 0;
            while (!flags_ge(fp, (unsigned int)t)) {
                if (++iters > (1 << 22)) break;
                __builtin_amdgcn_s_sleep(1);
            }
            __builtin_amdgcn_sched_barrier(0);
            // h_t: virgin addresses; issue ALL 64 loads, then register-only MFMA
            const unsigned short* hmt = hm + ((size_t)t << 16);
            u64 hlo[4][8], hhi[4][8];
            #pragma unroll
            for (int kk8 = 0; kk8 < 8; ++kk8) {
                int cb = (koff + kk8 * 32) >> 2;
                #pragma unroll
                for (int m = 0; m < 4; ++m) {
                    const unsigned short* p = hmt + (size_t)cb * 256 + (m * 16 + lrow) * 4;
                    hlo[m][kk8] = *(const u64*)p;
                    hhi[m][kk8] = *(const u64*)(p + 256);
                }
            }
            #pragma unroll
            for (int kk8 = 0; kk8 < 8; ++kk8)
                #pragma unroll
                for (int m = 0; m < 4; ++m)
                    acc[m] = __builtin_amdgcn_mfma_f32_16x16x32_bf16(frag2(hlo[m][kk8], hhi[m][kk8]),
                                                                     wfrag[kk8], acc[m], 0, 0, 0);
        }

        #pragma unroll
        for (int m = 0; m < 4; ++m)
            #pragma unroll
            for (int r = 0; r < 4; ++r)
                gxp[wave][m * 16 + qr + r][lrow] = acc[m][r];
        __syncthreads();   // S1: gate partials ready

        if (tid >= 256) {
            float fpre = bb.x, ipre = bb.y, opre = bb.z, gpre = bb.w;
            #pragma unroll
            for (int w = 0; w < 8; ++w) {
                float4 s = *(const float4*)&gxp[w][ob][lhc << 2];
                fpre += s.x; ipre += s.y; opre += s.z; gpre += s.w;
            }
            float fg = sigf(fpre);
            float ig = sigf(ipre);
            float og = sigf(opre);
            float gg = tanhfast(gpre);
            c_reg = fg * c_reg + ig * gg;
            float hh = og * tanhfast(c_reg);
            if (t == TSTEPS - 1) hlast = hh;

            // publish BEFORE S2: shfl-pack 4 bf16 -> one 8B store per 4 lanes
            unsigned int hb = f2b(hh);
            unsigned int p1 = __shfl_down(hb, 1);
            unsigned int p2 = __shfl_down(hb, 2);
            unsigned int p3 = __shfl_down(hb, 3);
            if ((lane & 3) == 0) {
                u64 v = (u64)hb | ((u64)p1 << 16) | ((u64)p2 << 32) | ((u64)p3 << 48);
                unsigned short* dst = hm + ((size_t)(t + 1) << 16) + (size_t)bid * 256 + (size_t)ob * 4;
                asm volatile("global_store_dwordx2 %0, %1, off sc0 sc1" :: "v"(dst), "v"(v) : "memory");
            }
            asm volatile("s_waitcnt vmcnt(0)" ::: "memory");
            if (wave != 7) {
                if (lane == 0) atomicAdd(&cnt, 1);
            } else if (lane == 0) {
                int spin = 0;
                while (*(volatile int*)&cnt < 3 * (t + 1)) {
                    if (++spin > (1 << 24)) break;
                }
                unsigned int* fdst = flags + bid;
                unsigned int fv = (unsigned int)(t + 1);
                asm volatile("global_store_dword %0, %1, off sc0 sc1" :: "v"(fdst), "v"(fv) : "memory");
            }
        }
        __syncthreads();   // S2: gxp consumed, safe to overwrite next step
    }

    if (tid >= 256) {
        out[(size_t)ob * HD + hcol] = c_reg;                    // c
        out[65536 + (size_t)ob * HD + hcol] = hlast;            // h
    }

    // final projection: last_out = h_256 @ V^T + V_b, blocks 0..63 (N=1024)
    if (bid < 64) {
        {
            const unsigned int* fp = flags + (lane << 2);
            int iters = 0;
            while (!flags_ge(fp, 256u)) {
                if (++iters > (1 << 22)) break;
                __builtin_amdgcn_s_sleep(1);
            }
        }
        __builtin_amdgcn_sched_barrier(0);
        f32x4 acc[4];
        #pragma unroll
        for (int m = 0; m < 4; ++m) acc[m] = (f32x4){0, 0, 0, 0};
        const int ko2 = (wave << 7) + kq;                       // K=1024 split 8 x 128
        const unsigned short* vp = Vw + (size_t)(n0 + lrow) * HD + ko2;
        const unsigned short* hmt = hm + ((size_t)TSTEPS << 16);
        #pragma unroll
        for (int kk = 0; kk < 128; kk += 32) {
            bf16x8 bfrag = *(const bf16x8*)(vp + kk);
            int cb = (ko2 + kk) >> 2;
            #pragma unroll
            for (int m = 0; m < 4; ++m) {
                const unsigned short* p = hmt + (size_t)cb * 256 + (m * 16 + lrow) * 4;
                u64 lo = *(const u64*)p;
                u64 hi = *(const u64*)(p + 256);
                acc[m] = __builtin_amdgcn_mfma_f32_16x16x32_bf16(frag2(lo, hi), bfrag, acc[m], 0, 0, 0);
            }
        }
        #pragma unroll
        for (int m = 0; m < 4; ++m)
            #pragma unroll
            for (int r = 0; r < 4; ++r)
                gxp[wave][m * 16 + qr + r][lrow] = acc[m][r];
        __syncthreads();
        if (tid >= 256) {
            float4 vb = *(const float4*)&Vbias[n0 + (lhc << 2)];
            float4 res = vb;
            #pragma unroll
            for (int w = 0; w < 8; ++w) {
                float4 s = *(const float4*)&gxp[w][ob][lhc << 2];
                res.x += s.x; res.y += s.y; res.z += s.z; res.w += s.w;
            }
            *(float4*)&out[131072 + (size_t)ob * 1024 + n0 + (lhc << 2)] = res;
        }
    }
}

extern "C" void kernel_launch(void* const* d_in, const int* in_sizes, int n_in,
                              void* d_out, int out_size, void* d_ws, size_t ws_size,
                              hipStream_t stream) {
    const float* x   = (const float*)d_in[0];
    const float* Wf  = (const float*)d_in[1];
    const float* bf_ = (const float*)d_in[2];
    const float* Wi  = (const float*)d_in[3];
    const float* bi_ = (const float*)d_in[4];
    const float* Wc  = (const float*)d_in[5];
    const float* bc_ = (const float*)d_in[6];
    const float* Wo  = (const float*)d_in[7];
    const float* bo_ = (const float*)d_in[8];
    const float* Vw  = (const float*)d_in[9];
    const float* Vb  = (const float*)d_in[10];

    char* ws = (char*)d_ws;
    unsigned short* Wr     = (unsigned short*)(ws + WOFF);
    unsigned short* Vbf    = (unsigned short*)(ws + VOFF);
    float*          bias_r = (float*)(ws + BOFF);
    unsigned short* hm     = (unsigned short*)(ws + HMOFF);
    unsigned int*   flags  = (unsigned int*)(ws + BAROFF);
    unsigned short* xbb    = (unsigned short*)(ws + XBOFF);
    float*          outp   = (float*)d_out;

    cvt_x <<<8192, 256, 0, stream>>>(x, xbb);
    cvt_w <<<4096, 256, 0, stream>>>(Wf, Wi, Wo, Wc, bf_, bi_, bo_, bc_, Wr, bias_r);
    cvt_v <<<512, 256, 0, stream>>>(Vw, Vbf);
    init_h<<<32, 256, 0, stream>>>(hm);
    init_bar<<<1, 256, 0, stream>>>(flags);

    void* args[] = {&xbb, &Wr, &bias_r, &hm, &Vbf, (void*)&Vb, &outp, &flags};
    hipLaunchCooperativeKernel((const void*)lstm_core, dim3(256), dim3(512), args, 0, stream);
}